// Round 6
// baseline (155.788 us; speedup 1.0000x reference)
//
#include <hip/hip_runtime.h>
#include <math.h>

#define NA 30
#define ND 435          // NA*(NA-1)/2
#define NI 90           // 3*NA
#define NP 12
#define NNB (NA-1)

typedef float v2f __attribute__((ext_vector_type(2)));

struct Pre {
  int   pidx[NP][ND];      // pair permutation: d -> image pair under perm p
  int   sigma[NP][NA];     // atom permutation
  int   sigma_inv[NP][NA];
  int   rowv[ND];
  int   colv[ND];
  float rjp[NP][ND];       // R_desc[j][pidx[p][d]]
  alignas(16) float spj[NA][NI];  // expanded antisym S' of point j: S'[a][u][c]
  // gtab[k][p][a]: d | u<<9 | sigma_p(u)<<14   (coalesced in a)
  unsigned int gtab[NNB][NP][NA];
  // stab[a][a2][p]: u | sa<<5 | valid<<31  (u = sigma_inv[p][a2], sa = sigma[p][a])
  alignas(16) unsigned int stab[NA][NA][NP];
  unsigned int hmask[NA][NA];   // bit p set iff sigma_p(a)==a2
};

__device__ __forceinline__ int pair_index(int x, int y) {
  int hi = max(x, y), lo = min(x, y);
  return hi * (hi - 1) / 2 + lo;
}

// ---- preA: small dependent graph work, single block ----
__global__ void preA_kernel(const int* __restrict__ tpl, Pre* ws) {
  const int tid = threadIdx.x;
  const int nthr = blockDim.x;

  for (int d = tid; d < ND; d += nthr) {
    int a = (int)floorf((1.0f + sqrtf(1.0f + 8.0f * (float)d)) * 0.5f);
    while (a * (a - 1) / 2 > d) --a;
    while ((a + 1) * a / 2 <= d) ++a;
    ws->rowv[d] = a;
    ws->colv[d] = d - a * (a - 1) / 2;
  }
  for (int idx = tid; idx < NP * ND; idx += nthr) {
    int d = idx / NP, p = idx % NP;          // tpl layout: [d*NP + p]
    ws->pidx[p][d] = tpl[idx] - p * ND;
  }
  __syncthreads();
  // recover atom permutation sigma_p
  for (int idx = tid; idx < NP * NA; idx += nthr) {
    int p = idx / NA, a = idx % NA;
    int u1 = (a == 0) ? 1 : 0;
    int u2 = (a <= 1) ? 2 : 1;
    int e1 = ws->pidx[p][pair_index(a, u1)];
    int e2 = ws->pidx[p][pair_index(a, u2)];
    int r1 = ws->rowv[e1], c1 = ws->colv[e1];
    int r2 = ws->rowv[e2], c2 = ws->colv[e2];
    int sa = (r1 == r2 || r1 == c2) ? r1 : c1;
    ws->sigma[p][a] = sa;
  }
  __syncthreads();
  for (int idx = tid; idx < NP * NA; idx += nthr) {
    int p = idx / NA, a = idx % NA;
    ws->sigma_inv[p][ws->sigma[p][a]] = a;
  }
  __syncthreads();
  for (int it = tid; it < NA * NA; it += nthr) {
    int a = it / NA, a2 = it % NA;
    unsigned m = 0;
#pragma unroll
    for (int p = 0; p < NP; ++p)
      if (ws->sigma[p][a] == a2) m |= (1u << p);
    ws->hmask[a][a2] = m;
  }
}

// ---- preB: bulk table fills, grid-parallel ----
__global__ void preB_kernel(const float* __restrict__ R_desc,
                            const float* __restrict__ R_d_desc,
                            const int* __restrict__ jptr,
                            Pre* ws) {
  const int gid = blockIdx.x * blockDim.x + threadIdx.x;
  const int gsz = gridDim.x * blockDim.x;
  const int j = *jptr;

  for (int idx = gid; idx < NP * ND; idx += gsz) {
    int p = idx / ND, d = idx % ND;
    ws->rjp[p][d] = R_desc[(size_t)j * ND + ws->pidx[p][d]];
  }
  // expanded antisymmetric S' of point j
  for (int idx = gid; idx < NA * NI; idx += gsz) {
    int a = idx / NI, r = idx % NI;
    int u = r / 3, c = r % 3;
    float val = 0.f;
    if (u != a) {
      int d = pair_index(a, u);
      float t = R_d_desc[(size_t)j * (ND * 3) + 3 * d + c];
      val = (a > u) ? t : -t;
    }
    ((float*)ws->spj)[idx] = val;
  }
  // gtab[k][p][a]
  for (int idx = gid; idx < NNB * NP * NA; idx += gsz) {
    int a = idx % NA;
    int r = idx / NA;
    int p = r % NP, k = r / NP;
    int u = k + (k >= a ? 1 : 0);
    int d = pair_index(a, u);
    int su = ws->sigma[p][u];
    ws->gtab[k][p][a] = (unsigned)d | ((unsigned)u << 9) | ((unsigned)su << 14);
  }
  // stab[a][a2][p]
  for (int idx = gid; idx < NA * NA * NP; idx += gsz) {
    int p = idx % NP;
    int r = idx / NP;
    int a2 = r % NA, a = r / NA;
    unsigned int v = 0;
    if (ws->sigma[p][a] != a2) {
      int u = ws->sigma_inv[p][a2];
      v = (unsigned)u | ((unsigned)ws->sigma[p][a] << 5) | (1u << 31);
    }
    ws->stab[a][a2][p] = v;
  }
}

__global__ __launch_bounds__(256, 3) void gdml_kernel(
    const float* __restrict__ R_desc,
    const float* __restrict__ R_d_desc,
    const Pre* __restrict__ ws,
    float* __restrict__ out) {
  const int n = blockIdx.x;
  const int tid = threadIdx.x;

  __shared__ float U[NP * ND];                 // 20.9 KB: xd, then Hh [NA][NP*9]
  __shared__ float S[NA * NI];                 // 10.8 KB expanded antisym Rdn (point n)
  __shared__ alignas(16) float Sp[NA * NI];    // 10.8 KB expanded antisym Rdj (point j)
  __shared__ float v_s[NP * NI];               // 4.3 KB (e_p * v)
  __shared__ float w_s[NP * NI];               // 4.3 KB (inner)
  __shared__ float dist2[NP];
  __shared__ float e_s[NP], e1_s[NP];
  // total ~51.3 KB -> 3 blocks/CU

  const float q   = 0.22360679774997896f;   // sqrt(5)/10
  const float qq3 = 0.016666666666666666f;  // q*q/3

  // ---- P1: fills ----
  if (tid < NP) dist2[tid] = 0.f;
  // S' linear copy (coalesced float4)
  {
    const float4* g4 = (const float4*)ws->spj;
    float4* s4 = (float4*)Sp;
    for (int idx = tid; idx < (NA * NI) / 4; idx += 256) s4[idx] = g4[idx];
  }
  // S expansion from R_d_desc[n] (L1-resident row)
  for (int idx = tid; idx < NA * NI; idx += 256) {
    int a = idx / NI, r = idx % NI;
    int u = r / 3, c = r % 3;
    float val = 0.f;
    if (u != a) {
      int d = pair_index(a, u);
      float t = R_d_desc[(size_t)n * (ND * 3) + 3 * d + c];
      val = (a > u) ? t : -t;
    }
    S[idx] = val;
  }
  // xd fill + per-thread dist partials
  {
    float acc[NP];
#pragma unroll
    for (int p = 0; p < NP; ++p) acc[p] = 0.f;
    for (int d = tid; d < ND; d += 256) {
      float rn = R_desc[(size_t)n * ND + d];
#pragma unroll
      for (int p = 0; p < NP; ++p) {
        float x = q * (rn - ws->rjp[p][d]);
        U[p * ND + d] = x;
        acc[p] += x * x;
      }
    }
#pragma unroll
    for (int p = 0; p < NP; ++p) {
      float a = acc[p];
      for (int off = 32; off; off >>= 1) a += __shfl_xor(a, off);
      if ((tid & 63) == 0) atomicAdd(&dist2[p], a);
    }
  }
  __syncthreads();
  if (tid < NP) {
    float dist = sqrtf(dist2[tid]);
    float e = expf(-dist) * qq3;
    e_s[tid] = e;
    e1_s[tid] = e * (1.f + dist);
  }
  __syncthreads();

  // ---- P2': per (p,a): v[p][a], inner[p][sigma_p(a)], heavy H (in regs) ----
  auto p2_item = [&](int it, float (&h)[9]) {
    int a = it % NA, p = it / NA;
    int sa = ws->sigma[p][a];
    const float* xdp = U + p * ND;
    const float* Srow = S + a * NI;
    const float* Prow = Sp + sa * NI;
    v2f V01 = {0.f, 0.f}; float V2 = 0.f;
    v2f I01 = {0.f, 0.f}; float I2 = 0.f;
    v2f H0 = {0.f, 0.f}, H1 = {0.f, 0.f}, H2 = {0.f, 0.f};
    float Hc0 = 0.f, Hc1 = 0.f, Hc2 = 0.f;
    for (int k = 0; k < NNB; ++k) {
      unsigned g = ws->gtab[k][p][a];
      int d  = g & 511;
      int u  = (g >> 9) & 31;
      int su = (g >> 14) & 31;
      float x  = xdp[d];
      float s0 = Srow[3 * u], s1 = Srow[3 * u + 1], s2 = Srow[3 * u + 2];
      float t0 = Prow[3 * su], t1 = Prow[3 * su + 1], t2 = Prow[3 * su + 2];
      V01 += (v2f){x, x} * (v2f){s0, s1}; V2 += x * s2;
      I01 += (v2f){x, x} * (v2f){t0, t1}; I2 += x * t2;
      v2f t01 = {t0, t1};
      H0 += (v2f){s0, s0} * t01; Hc0 += s0 * t2;
      H1 += (v2f){s1, s1} * t01; Hc1 += s1 * t2;
      H2 += (v2f){s2, s2} * t01; Hc2 += s2 * t2;
    }
    float e = e_s[p];
    v_s[p * NI + 3 * a + 0] = e * V01.x;
    v_s[p * NI + 3 * a + 1] = e * V01.y;
    v_s[p * NI + 3 * a + 2] = e * V2;
    w_s[p * NI + 3 * sa + 0] = I01.x;
    w_s[p * NI + 3 * sa + 1] = I01.y;
    w_s[p * NI + 3 * sa + 2] = I2;
    h[0] = H0.x; h[1] = H0.y; h[2] = Hc0;
    h[3] = H1.x; h[4] = H1.y; h[5] = Hc1;
    h[6] = H2.x; h[7] = H2.y; h[8] = Hc2;
  };

  float h1[9], h2[9];
  const int it1 = tid;
  const int it2 = tid + 256;
  const bool has2 = (it2 < NP * NA);
  p2_item(it1, h1);
  if (has2) p2_item(it2, h2);
  __syncthreads();   // xd dead -> U becomes Hh

  {
    int a = it1 % NA, p = it1 / NA;
    float* hb = U + a * (NP * 9) + p * 9;
#pragma unroll
    for (int r = 0; r < 9; ++r) hb[r] = h1[r];
  }
  if (has2) {
    int a = it2 % NA, p = it2 / NA;
    float* hb = U + a * (NP * 9) + p * 9;
#pragma unroll
    for (int r = 0; r < 9; ++r) hb[r] = h2[r];
  }
  __syncthreads();

  // ---- P5: fused output, one thread per (a,a2) 3x3 block ----
  float e1r[NP];
#pragma unroll
  for (int p = 0; p < NP; ++p) e1r[p] = e1_s[p];

  float* outn = out + (size_t)n * (NI * NI);
  for (int it = tid; it < NA * NA; it += 256) {
    int a = it / NA, a2 = it % NA;
    v2f A0 = {0.f, 0.f}, A1 = {0.f, 0.f}, A2 = {0.f, 0.f};
    float B0 = 0.f, B1 = 0.f, B2 = 0.f;
    const float* Srow = S + a * NI;
    const uint4* st4 = (const uint4*)&ws->stab[a][a2][0];
    uint4 ua = st4[0], ub = st4[1], uc = st4[2];
    unsigned stv[12] = {ua.x, ua.y, ua.z, ua.w, ub.x, ub.y, ub.z, ub.w,
                        uc.x, uc.y, uc.z, uc.w};
#pragma unroll
    for (int p = 0; p < NP; ++p) {
      // rank-12 part
      float v0 = v_s[p * NI + 3 * a + 0];
      float v1 = v_s[p * NI + 3 * a + 1];
      float v2v = v_s[p * NI + 3 * a + 2];
      float w0 = w_s[p * NI + 3 * a2 + 0];
      float w1 = w_s[p * NI + 3 * a2 + 1];
      float w2 = w_s[p * NI + 3 * a2 + 2];
      v2f w01 = {w0, w1};
      A0 += (v2f){v0, v0} * w01;   B0 += v0 * w2;
      A1 += (v2f){v1, v1} * w01;   B1 += v1 * w2;
      A2 += (v2f){v2v, v2v} * w01; B2 += v2v * w2;
      // single-term: +e1p * S[a][u] (x) S'[sa][a2]  (signs baked in)
      unsigned g = stv[p];
      float f = (g >> 31) ? e1r[p] : 0.f;
      int u  = g & 31;
      int sa = (g >> 5) & 31;
      float r0 = f * Srow[3 * u];
      float r1 = f * Srow[3 * u + 1];
      float r2 = f * Srow[3 * u + 2];
      float j0 = Sp[sa * NI + 3 * a2 + 0];
      float j1 = Sp[sa * NI + 3 * a2 + 1];
      float j2 = Sp[sa * NI + 3 * a2 + 2];
      v2f j01 = {j0, j1};
      A0 += (v2f){r0, r0} * j01; B0 += r0 * j2;
      A1 += (v2f){r1, r1} * j01; B1 += r1 * j2;
      A2 += (v2f){r2, r2} * j01; B2 += r2 * j2;
    }
    unsigned m = ws->hmask[a][a2];
    while (m) {
      int p = __ffs(m) - 1;
      m &= m - 1;
      float e1 = e1r[p];
      const float* hb = U + a * (NP * 9) + p * 9;
      A0 -= e1 * (v2f){hb[0], hb[1]}; B0 -= e1 * hb[2];
      A1 -= e1 * (v2f){hb[3], hb[4]}; B1 -= e1 * hb[5];
      A2 -= e1 * (v2f){hb[6], hb[7]}; B2 -= e1 * hb[8];
    }
    float* ob = outn + (size_t)(3 * a) * NI + 3 * a2;
    ob[0] = A0.x;          ob[1] = A0.y;          ob[2] = B0;
    ob[NI + 0] = A1.x;     ob[NI + 1] = A1.y;     ob[NI + 2] = B1;
    ob[2 * NI + 0] = A2.x; ob[2 * NI + 1] = A2.y; ob[2 * NI + 2] = B2;
  }
}

extern "C" void kernel_launch(void* const* d_in, const int* in_sizes, int n_in,
                              void* d_out, int out_size, void* d_ws, size_t ws_size,
                              hipStream_t stream) {
  const float* R_desc   = (const float*)d_in[0];
  const float* R_d_desc = (const float*)d_in[1];
  const int*   tpl      = (const int*)d_in[2];
  const int*   jptr     = (const int*)d_in[3];
  float* out = (float*)d_out;
  Pre* ws = (Pre*)d_ws;

  const int n_train = in_sizes[0] / ND;

  hipLaunchKernelGGL(preA_kernel, dim3(1), dim3(256), 0, stream, tpl, ws);
  hipLaunchKernelGGL(preB_kernel, dim3(48), dim3(256), 0, stream,
                     R_desc, R_d_desc, jptr, ws);
  hipLaunchKernelGGL(gdml_kernel, dim3(n_train), dim3(256), 0, stream,
                     R_desc, R_d_desc, ws, out);
}

// Round 7
// 88.356 us; speedup vs baseline: 1.7632x; 1.7632x over previous
//
#include <hip/hip_runtime.h>
#include <math.h>

#define NA 30
#define ND 435          // NA*(NA-1)/2
#define NI 90           // 3*NA
#define NP 12
#define NNB (NA-1)

typedef float v2f __attribute__((ext_vector_type(2)));

struct Pre {
  int   pidx[NP][ND];      // pair permutation: d -> image pair under perm p
  int   sigma[NP][NA];     // atom permutation
  int   sigma_inv[NP][NA];
  int   rowv[ND];
  int   colv[ND];
  float rjp[NP][ND];       // R_desc[j][pidx[p][d]]
  alignas(16) float spj[NA][NI];  // expanded antisym S' of point j: sign(a,u)*Rdj[pair(a,u)][c]
  // gtab[k][p][a]: d | su<<9 | s1<<14      (coalesced in a; u = k+(k>=a), su = sigma_p(u), s1 = a>u)
  unsigned int gtab[NNB][NP][NA];
  // stab[a][a2][p]: d1 | sa<<9 | s1<<14 | valid<<15
  alignas(16) unsigned int stab[NA][NA][NP];
  unsigned int hmask[NA][NA];   // bit p set iff sigma_p(a)==a2
};

__device__ __forceinline__ int pair_index(int x, int y) {
  int hi = max(x, y), lo = min(x, y);
  return hi * (hi - 1) / 2 + lo;
}

// ---- preA: small dependent graph work, single block ----
__global__ void preA_kernel(const int* __restrict__ tpl, Pre* ws) {
  const int tid = threadIdx.x;
  const int nthr = blockDim.x;

  for (int d = tid; d < ND; d += nthr) {
    int a = (int)floorf((1.0f + sqrtf(1.0f + 8.0f * (float)d)) * 0.5f);
    while (a * (a - 1) / 2 > d) --a;
    while ((a + 1) * a / 2 <= d) ++a;
    ws->rowv[d] = a;
    ws->colv[d] = d - a * (a - 1) / 2;
  }
  for (int idx = tid; idx < NP * ND; idx += nthr) {
    int d = idx / NP, p = idx % NP;          // tpl layout: [d*NP + p]
    ws->pidx[p][d] = tpl[idx] - p * ND;
  }
  __syncthreads();
  // recover atom permutation sigma_p
  for (int idx = tid; idx < NP * NA; idx += nthr) {
    int p = idx / NA, a = idx % NA;
    int u1 = (a == 0) ? 1 : 0;
    int u2 = (a <= 1) ? 2 : 1;
    int e1 = ws->pidx[p][pair_index(a, u1)];
    int e2 = ws->pidx[p][pair_index(a, u2)];
    int r1 = ws->rowv[e1], c1 = ws->colv[e1];
    int r2 = ws->rowv[e2], c2 = ws->colv[e2];
    int sa = (r1 == r2 || r1 == c2) ? r1 : c1;
    ws->sigma[p][a] = sa;
  }
  __syncthreads();
  for (int idx = tid; idx < NP * NA; idx += nthr) {
    int p = idx / NA, a = idx % NA;
    ws->sigma_inv[p][ws->sigma[p][a]] = a;
  }
  __syncthreads();
  for (int it = tid; it < NA * NA; it += nthr) {
    int a = it / NA, a2 = it % NA;
    unsigned m = 0;
#pragma unroll
    for (int p = 0; p < NP; ++p)
      if (ws->sigma[p][a] == a2) m |= (1u << p);
    ws->hmask[a][a2] = m;
  }
}

// ---- preB: bulk table fills, grid-parallel ----
__global__ void preB_kernel(const float* __restrict__ R_desc,
                            const float* __restrict__ R_d_desc,
                            const int* __restrict__ jptr,
                            Pre* ws) {
  const int gid = blockIdx.x * blockDim.x + threadIdx.x;
  const int gsz = gridDim.x * blockDim.x;
  const int j = *jptr;

  for (int idx = gid; idx < NP * ND; idx += gsz) {
    int p = idx / ND, d = idx % ND;
    ws->rjp[p][d] = R_desc[(size_t)j * ND + ws->pidx[p][d]];
  }
  // expanded antisymmetric S' of point j
  for (int idx = gid; idx < NA * NI; idx += gsz) {
    int a = idx / NI, r = idx % NI;
    int u = r / 3, c = r % 3;
    float val = 0.f;
    if (u != a) {
      int d = pair_index(a, u);
      float t = R_d_desc[(size_t)j * (ND * 3) + 3 * d + c];
      val = (a > u) ? t : -t;
    }
    ((float*)ws->spj)[idx] = val;
  }
  // gtab[k][p][a]
  for (int idx = gid; idx < NNB * NP * NA; idx += gsz) {
    int a = idx % NA;
    int r = idx / NA;
    int p = r % NP, k = r / NP;
    int u = k + (k >= a ? 1 : 0);
    int d = pair_index(a, u);
    int su = ws->sigma[p][u];
    unsigned g = (unsigned)d | ((unsigned)su << 9);
    if (a > u) g |= (1u << 14);
    ws->gtab[k][p][a] = g;
  }
  // stab[a][a2][p]
  for (int idx = gid; idx < NA * NA * NP; idx += gsz) {
    int p = idx % NP;
    int r = idx / NP;
    int a2 = r % NA, a = r / NA;
    unsigned int v = 0;
    if (ws->sigma[p][a] != a2) {
      int u = ws->sigma_inv[p][a2];
      int d1 = pair_index(a, u);
      int sa = ws->sigma[p][a];
      v = (unsigned)d1 | ((unsigned)sa << 9) | (1u << 15);
      if (a > u) v |= (1u << 14);
    }
    ws->stab[a][a2][p] = v;
  }
}

__global__ __launch_bounds__(256, 4) void gdml_kernel(
    const float* __restrict__ R_desc,
    const float* __restrict__ R_d_desc,
    const Pre* __restrict__ ws,
    float* __restrict__ out) {
  const int n = blockIdx.x;
  const int tid = threadIdx.x;

  __shared__ float rn_l[ND];          // 1.74 KB  R_desc[n]
  __shared__ float Rdn_l[ND * 3];     // 5.22 KB  R_d_desc[n]
  __shared__ alignas(16) float Sp[NA * NI];  // 10.8 KB expanded antisym Rdj (point j)
  __shared__ float v_s[NP * NI];      // 4.32 KB
  __shared__ float w_s[NP * NI];      // 4.32 KB
  __shared__ float Hh[NA * NP * 9];   // 12.96 KB heavy 3x3 blocks
  __shared__ float dist2[NP];
  __shared__ float e_s[NP], e1_s[NP];
  // total ~38.6 KB -> 4 blocks/CU

  const float q   = 0.22360679774997896f;   // sqrt(5)/10
  const float qq3 = 0.016666666666666666f;  // q*q/3

  // ---- P0: coalesced fills ----
  if (tid < NP) dist2[tid] = 0.f;
  for (int d = tid; d < ND; d += 256) rn_l[d] = R_desc[(size_t)n * ND + d];
  for (int i = tid; i < ND * 3; i += 256)
    Rdn_l[i] = R_d_desc[(size_t)n * (ND * 3) + i];
  {
    const float4* g4 = (const float4*)ws->spj;
    float4* s4 = (float4*)Sp;
    for (int i = tid; i < (NA * NI) / 4; i += 256) s4[i] = g4[i];
  }
  __syncthreads();

  // ---- P2: per (p,a): v[p][a], inner[p][sigma_p(a)], heavy H (regs), dist partial ----
  auto p2_item = [&](int it, float (&h)[9]) {
    int a = it % NA, p = it / NA;
    int sa = ws->sigma[p][a];
    const float* Prow = Sp + sa * NI;
    const float* rjpp = &ws->rjp[p][0];
    v2f V01 = {0.f, 0.f}; float V2 = 0.f;
    v2f I01 = {0.f, 0.f}; float I2 = 0.f;
    v2f H0 = {0.f, 0.f}, H1 = {0.f, 0.f}, H2 = {0.f, 0.f};
    float Hc0 = 0.f, Hc1 = 0.f, Hc2 = 0.f;
    float xq = 0.f;
    for (int k = 0; k < NNB; ++k) {
      unsigned g = ws->gtab[k][p][a];
      int d  = g & 511;
      int su = (g >> 9) & 31;
      float s1 = (g & (1u << 14)) ? 1.f : -1.f;
      float x = q * (rn_l[d] - rjpp[d]);
      xq += x * x;
      float n0 = Rdn_l[3 * d], n1 = Rdn_l[3 * d + 1], n2 = Rdn_l[3 * d + 2];
      float t0 = Prow[3 * su], t1 = Prow[3 * su + 1], t2 = Prow[3 * su + 2];
      float sx = s1 * x;
      V01 += (v2f){sx, sx} * (v2f){n0, n1}; V2 += sx * n2;
      I01 += (v2f){x, x} * (v2f){t0, t1};   I2 += x * t2;
      float sn0 = s1 * n0, sn1 = s1 * n1, sn2 = s1 * n2;
      v2f t01 = {t0, t1};
      H0 += (v2f){sn0, sn0} * t01; Hc0 += sn0 * t2;
      H1 += (v2f){sn1, sn1} * t01; Hc1 += sn1 * t2;
      H2 += (v2f){sn2, sn2} * t01; Hc2 += sn2 * t2;
    }
    v_s[p * NI + 3 * a + 0] = V01.x;   // unscaled; e applied later
    v_s[p * NI + 3 * a + 1] = V01.y;
    v_s[p * NI + 3 * a + 2] = V2;
    w_s[p * NI + 3 * sa + 0] = I01.x;
    w_s[p * NI + 3 * sa + 1] = I01.y;
    w_s[p * NI + 3 * sa + 2] = I2;
    atomicAdd(&dist2[p], xq);
    h[0] = H0.x; h[1] = H0.y; h[2] = Hc0;
    h[3] = H1.x; h[4] = H1.y; h[5] = Hc1;
    h[6] = H2.x; h[7] = H2.y; h[8] = Hc2;
  };

  float h1[9], h2[9];
  const int it1 = tid;
  const int it2 = tid + 256;
  const bool has2 = (it2 < NP * NA);
  p2_item(it1, h1);
  if (has2) p2_item(it2, h2);
  __syncthreads();

  // ---- e/e1 (each (p,d) counted twice in dist2) + Hh stores ----
  if (tid < NP) {
    float dist = sqrtf(dist2[tid] * 0.5f);
    float e = expf(-dist) * qq3;
    e_s[tid] = e;
    e1_s[tid] = e * (1.f + dist);
  }
  {
    int a = it1 % NA, p = it1 / NA;
    float* hb = &Hh[(a * NP + p) * 9];
#pragma unroll
    for (int r = 0; r < 9; ++r) hb[r] = h1[r];
  }
  if (has2) {
    int a = it2 % NA, p = it2 / NA;
    float* hb = &Hh[(a * NP + p) * 9];
#pragma unroll
    for (int r = 0; r < 9; ++r) hb[r] = h2[r];
  }
  __syncthreads();

  // ---- scale v by e_p ----
  for (int i = tid; i < NP * NI; i += 256) v_s[i] *= e_s[i / NI];
  __syncthreads();

  // ---- P5: fused output, one thread per (a,a2) 3x3 block ----
  float e1r[NP];
#pragma unroll
  for (int p = 0; p < NP; ++p) e1r[p] = e1_s[p];

  float* outn = out + (size_t)n * (NI * NI);
  for (int it = tid; it < NA * NA; it += 256) {
    int a = it / NA, a2 = it % NA;
    v2f A0 = {0.f, 0.f}, A1 = {0.f, 0.f}, A2 = {0.f, 0.f};
    float B0 = 0.f, B1 = 0.f, B2 = 0.f;
    const uint4* st4 = (const uint4*)&ws->stab[a][a2][0];
    uint4 ua = st4[0], ub = st4[1], uc = st4[2];
    unsigned stv[12] = {ua.x, ua.y, ua.z, ua.w, ub.x, ub.y, ub.z, ub.w,
                        uc.x, uc.y, uc.z, uc.w};
#pragma unroll
    for (int p = 0; p < NP; ++p) {
      // rank-12 part: v broadcast, w stride-3 (conflict-free)
      float v0 = v_s[p * NI + 3 * a + 0];
      float v1 = v_s[p * NI + 3 * a + 1];
      float v2v = v_s[p * NI + 3 * a + 2];
      float w0 = w_s[p * NI + 3 * a2 + 0];
      float w1 = w_s[p * NI + 3 * a2 + 1];
      float w2 = w_s[p * NI + 3 * a2 + 2];
      v2f w01 = {w0, w1};
      A0 += (v2f){v0, v0} * w01;   B0 += v0 * w2;
      A1 += (v2f){v1, v1} * w01;   B1 += v1 * w2;
      A2 += (v2f){v2v, v2v} * w01; B2 += v2v * w2;
      // single-term: +e1p*s1 * Rdn[d1] (x) Sp[sa][a2]
      unsigned g = stv[p];
      float e1 = e1r[p];
      float fs = (g & (1u << 15)) ? ((g & (1u << 14)) ? e1 : -e1) : 0.f;
      int d1 = g & 511;
      int sa = (g >> 9) & 31;
      float r0 = fs * Rdn_l[3 * d1];
      float r1 = fs * Rdn_l[3 * d1 + 1];
      float r2 = fs * Rdn_l[3 * d1 + 2];
      float j0 = Sp[sa * NI + 3 * a2 + 0];
      float j1 = Sp[sa * NI + 3 * a2 + 1];
      float j2 = Sp[sa * NI + 3 * a2 + 2];
      v2f j01 = {j0, j1};
      A0 += (v2f){r0, r0} * j01; B0 += r0 * j2;
      A1 += (v2f){r1, r1} * j01; B1 += r1 * j2;
      A2 += (v2f){r2, r2} * j01; B2 += r2 * j2;
    }
    unsigned m = ws->hmask[a][a2];
    while (m) {
      int p = __ffs(m) - 1;
      m &= m - 1;
      float e1 = e1r[p];
      const float* hb = &Hh[(a * NP + p) * 9];
      A0 -= e1 * (v2f){hb[0], hb[1]}; B0 -= e1 * hb[2];
      A1 -= e1 * (v2f){hb[3], hb[4]}; B1 -= e1 * hb[5];
      A2 -= e1 * (v2f){hb[6], hb[7]}; B2 -= e1 * hb[8];
    }
    float* ob = outn + (size_t)(3 * a) * NI + 3 * a2;
    ob[0] = A0.x;          ob[1] = A0.y;          ob[2] = B0;
    ob[NI + 0] = A1.x;     ob[NI + 1] = A1.y;     ob[NI + 2] = B1;
    ob[2 * NI + 0] = A2.x; ob[2 * NI + 1] = A2.y; ob[2 * NI + 2] = B2;
  }
}

extern "C" void kernel_launch(void* const* d_in, const int* in_sizes, int n_in,
                              void* d_out, int out_size, void* d_ws, size_t ws_size,
                              hipStream_t stream) {
  const float* R_desc   = (const float*)d_in[0];
  const float* R_d_desc = (const float*)d_in[1];
  const int*   tpl      = (const int*)d_in[2];
  const int*   jptr     = (const int*)d_in[3];
  float* out = (float*)d_out;
  Pre* ws = (Pre*)d_ws;

  const int n_train = in_sizes[0] / ND;

  hipLaunchKernelGGL(preA_kernel, dim3(1), dim3(256), 0, stream, tpl, ws);
  hipLaunchKernelGGL(preB_kernel, dim3(48), dim3(256), 0, stream,
                     R_desc, R_d_desc, jptr, ws);
  hipLaunchKernelGGL(gdml_kernel, dim3(n_train), dim3(256), 0, stream,
                     R_desc, R_d_desc, ws, out);
}